// Round 6
// baseline (799.777 us; speedup 1.0000x reference)
//
#include <hip/hip_runtime.h>

// Slot attention, MI355X. B=64,N=4096,S=8,D=256,H=512,ITERS=3.
#define BB 64
#define NN 4096
#define SS 8
#define DD 256
#define HH 512
#define NCH 8
#define CHK 512
#define LSP 516  // padded row stride (f32) for logits LDS

typedef __attribute__((ext_vector_type(4))) float f32x4;
typedef __attribute__((ext_vector_type(8))) short short8;
typedef __attribute__((ext_vector_type(8))) __bf16 bf16x8;

static __device__ __forceinline__ f32x4 MFMA(short8 a, short8 b, f32x4 c){
  return __builtin_amdgcn_mfma_f32_16x16x32_bf16(
      __builtin_bit_cast(bf16x8, a), __builtin_bit_cast(bf16x8, b), c, 0, 0, 0);
}

static __device__ __forceinline__ unsigned short f2bf(float f){
  unsigned int x = __builtin_bit_cast(unsigned int, f);
  x += 0x7FFFu + ((x >> 16) & 1u);
  return (unsigned short)(x >> 16);
}

static __device__ __forceinline__ unsigned int pk2(float a, float b){
  return (unsigned int)f2bf(a) | ((unsigned int)f2bf(b) << 16);
}

// ---- merged weight pack + counter zero
struct PackDesc {
  const float* src[7];
  unsigned short* dst[7];
  int ET[7];
  int K[7];
  int blkStart[8];
};

__global__ void pack_all_kernel(PackDesc pd, int* __restrict__ done){
  if(blockIdx.x == 0 && threadIdx.x < BB) done[threadIdx.x] = 0;
  int blk = blockIdx.x;
  int seg = 0;
  #pragma unroll
  for(int i = 1; i < 7; ++i) if(blk >= pd.blkStart[i]) seg = i;
  int tid = (blk - pd.blkStart[seg]) * 256 + threadIdx.x;
  int ET = pd.ET[seg], K = pd.K[seg];
  if(tid >= ET * 16 * K) return;
  int i    = tid & 7;
  int lane = (tid >> 3) & 63;
  int rest = tid >> 9;
  int et = rest % ET;
  int kk = rest / ET;
  int row = et * 16 + (lane & 15);
  int col = kk * 32 + ((lane >> 4) << 3) + i;
  pd.dst[seg][tid] = f2bf(pd.src[seg][(size_t)row * K + col]);
}

// LN(inputs) -> x(bf16, LDS, swizzled) -> K row-major ; V^T [b][d][n].
// Row dimension processed in 2 halves (af[2][8]) to cut register pressure.
__global__ __launch_bounds__(256, 2) void proj_kernel(
    const float* __restrict__ inp, const float* __restrict__ g, const float* __restrict__ bta,
    const short8* __restrict__ wkp, const short8* __restrict__ wvp,
    unsigned short* __restrict__ kout, unsigned short* __restrict__ vT)
{
  __shared__ unsigned short xs[64 * 256];      // 32 KB LN'd input tile
  __shared__ unsigned short vstage[4][1024];   // 8 KB per-warp V^T staging
  const int t = threadIdx.x, w = t >> 6, l = t & 63;
  const size_t row0 = (size_t)blockIdx.x * 64;
  const int b = (int)(row0 >> 12);
  const int n_base = (int)(row0 & 4095);
  const int li = l & 15, lg = l >> 4;

  // LN: 16 lanes per row, 4 rows in flight per warp
  {
    float4 gg[4], bb[4];
    #pragma unroll
    for(int q = 0; q < 4; ++q){
      gg[q] = ((const float4*)g)[li + q * 16];
      bb[q] = ((const float4*)bta)[li + q * 16];
    }
    #pragma unroll
    for(int rr = 0; rr < 4; ++rr){
      int r = w * 16 + rr * 4 + lg;
      const float4* rp = (const float4*)(inp + (row0 + r) * DD);
      float4 x[4];
      #pragma unroll
      for(int q = 0; q < 4; ++q) x[q] = rp[li + q * 16];
      float s1 = 0.f, s2 = 0.f;
      #pragma unroll
      for(int q = 0; q < 4; ++q){
        s1 += x[q].x + x[q].y + x[q].z + x[q].w;
        s2 += x[q].x*x[q].x + x[q].y*x[q].y + x[q].z*x[q].z + x[q].w*x[q].w;
      }
      #pragma unroll
      for(int o = 8; o >= 1; o >>= 1){ s1 += __shfl_xor(s1, o); s2 += __shfl_xor(s2, o); }
      float mean = s1 * (1.0f/256.0f);
      float inv  = rsqrtf(s2 * (1.0f/256.0f) - mean*mean + 1e-5f);
      #pragma unroll
      for(int q = 0; q < 4; ++q){
        float y0 = (x[q].x-mean)*inv*gg[q].x + bb[q].x;
        float y1 = (x[q].y-mean)*inv*gg[q].y + bb[q].y;
        float y2 = (x[q].z-mean)*inv*gg[q].z + bb[q].z;
        float y3 = (x[q].w-mean)*inv*gg[q].w + bb[q].w;
        int byte = r * 512 + ((q * 128 + li * 8) ^ ((r & 7) << 4));
        *(uint2*)((char*)xs + byte) = make_uint2(pk2(y0,y1), pk2(y2,y3));
      }
    }
  }
  __syncthreads();

  const int et0 = w * 4;
  #pragma unroll
  for(int half = 0; half < 2; ++half){
    // A-fragments for this half: rows half*32 .. half*32+31 (2 row-groups of 16)
    short8 af[2][8];
    #pragma unroll
    for(int rg = 0; rg < 2; ++rg){
      int r = (half * 2 + rg) * 16 + li;
      #pragma unroll
      for(int kk = 0; kk < 8; ++kk){
        int ab = r * 512 + (((kk * 64) + (lg << 4)) ^ ((r & 7) << 4));
        af[rg][kk] = *(const short8*)((const char*)xs + ab);
      }
    }
    // K: swapped operands; lane holds 4 consecutive d; direct 8B stores.
    #pragma unroll
    for(int el = 0; el < 4; ++el){
      const int et = et0 + el;
      short8 wb[8];
      #pragma unroll
      for(int kk = 0; kk < 8; ++kk) wb[kk] = wkp[((kk * 16 + et) << 6) + l];
      #pragma unroll
      for(int rg = 0; rg < 2; ++rg){
        f32x4 a = (f32x4){0,0,0,0};
        #pragma unroll
        for(int kk = 0; kk < 8; ++kk) a = MFMA(wb[kk], af[rg][kk], a);
        size_t row = row0 + (half * 2 + rg) * 16 + li;
        int colb = et * 16 + (lg << 2);
        *(uint2*)(kout + row * DD + colb) = make_uint2(pk2(a[0],a[1]), pk2(a[2],a[3]));
      }
    }
    // V: direct operands; stage per-warp in LDS; coalesced 16B stores of V^T rows.
    #pragma unroll
    for(int el = 0; el < 4; ++el){
      const int et = et0 + el;
      short8 wb[8];
      #pragma unroll
      for(int kk = 0; kk < 8; ++kk) wb[kk] = wvp[((kk * 16 + et) << 6) + l];
      char* vs = (char*)&vstage[w][0];
      #pragma unroll
      for(int rg = 0; rg < 2; ++rg){
        f32x4 a = (f32x4){0,0,0,0};
        #pragma unroll
        for(int kk = 0; kk < 8; ++kk) a = MFMA(af[rg][kk], wb[kk], a);
        int nloc = (half * 2 + rg) * 16 + (lg << 2);
        int byte = li * 128 + ((nloc * 2) ^ ((li & 7) << 4));
        *(uint2*)(vs + byte) = make_uint2(pk2(a[0],a[1]), pk2(a[2],a[3]));
      }
      asm volatile("s_waitcnt lgkmcnt(0)" ::: "memory");
      {
        int dl = l >> 2, nb = l & 3;
        int byte = dl * 128 + (((half * 64) + nb * 16) ^ ((dl & 7) << 4));
        uint4 vv = *(uint4*)(vs + byte);
        int d = et * 16 + dl;
        *(uint4*)(vT + ((size_t)(b * 256 + d) << 12) + n_base + half * 32 + nb * 8) = vv;
      }
      asm volatile("" ::: "memory");
    }
  }
}

// slots0 = mu + exp(log_sigma)*noise ; q = LN_slots(slots0)@Wq^T * D^-0.5
__global__ __launch_bounds__(256, 1) void init_kernel(
    const float* __restrict__ noise, const float* __restrict__ mu, const float* __restrict__ lsg,
    const float* __restrict__ lng, const float* __restrict__ lnb,
    const short8* __restrict__ wqp, float* __restrict__ slots, float* __restrict__ qbuf)
{
  const int b = blockIdx.x, t = threadIdx.x, w = t >> 6, l = t & 63;
  __shared__ float SLN[SS * DD];
  __shared__ unsigned short A1[16 * DD];
  float muv = mu[t];
  float sgv = __expf(lsg[t]);
  #pragma unroll
  for(int s = 0; s < SS; ++s){
    float v = muv + sgv * noise[(size_t)b * 2048 + s * 256 + t];
    slots[(size_t)b * 2048 + s * 256 + t] = v;
    SLN[s * 256 + t] = v;
  }
  __syncthreads();
  float4 g4 = ((const float4*)lng)[l], bb4 = ((const float4*)lnb)[l];
  for(int sh = 0; sh < 2; ++sh){
    int s = w * 2 + sh;
    float4 x4 = ((const float4*)(SLN + s * 256))[l];
    float s1 = x4.x + x4.y + x4.z + x4.w;
    float s2 = x4.x*x4.x + x4.y*x4.y + x4.z*x4.z + x4.w*x4.w;
    #pragma unroll
    for(int o = 32; o >= 1; o >>= 1){ s1 += __shfl_xor(s1, o); s2 += __shfl_xor(s2, o); }
    float mean = s1 * (1.0f/256.0f);
    float inv  = rsqrtf(s2 * (1.0f/256.0f) - mean*mean + 1e-5f);
    float y0 = (x4.x-mean)*inv*g4.x + bb4.x;
    float y1 = (x4.y-mean)*inv*g4.y + bb4.y;
    float y2 = (x4.z-mean)*inv*g4.z + bb4.z;
    float y3 = (x4.w-mean)*inv*g4.w + bb4.w;
    int byte = s * 512 + ((l * 8) ^ ((s & 7) << 4));
    *(uint2*)((char*)A1 + byte) = make_uint2(pk2(y0,y1), pk2(y2,y3));
  }
  __syncthreads();
  const int m = l & 15;
  short8 af[8];
  #pragma unroll
  for(int kk = 0; kk < 8; ++kk){
    int ab = m * 512 + (((kk * 64) + ((l >> 4) << 4)) ^ ((m & 7) << 4));
    af[kk] = *(const short8*)((const char*)A1 + ab);
  }
  #pragma unroll
  for(int i = 0; i < 4; ++i){
    int et = w + i * 4;
    f32x4 c = (f32x4){0,0,0,0};
    #pragma unroll
    for(int kk = 0; kk < 8; ++kk) c = MFMA(af[kk], wqp[((kk * 16 + et) << 6) + l], c);
    int e = et * 16 + (l & 15);
    #pragma unroll
    for(int j = 0; j < 4; ++j){
      int s = ((l >> 4) << 2) + j;
      if(s < 8) qbuf[(size_t)b * 2048 + s * 256 + e] = c[j] * 0.0625f;
    }
  }
}

// Fused: MFMA flash-attention partials + last-block-per-batch update tail.
// LDS arena (manually aliased):
//   attn:   ls (f32 8*LSP = 16512 B) at [0, 16512)
//   update: A1 [0,8K) A2 [8K,16K) A3 [16K,32K) ;
//           gates GR [0,8K) GZ [8K,16K) GXN [16K,24K) GHN [24K,32K) (alias, after sync);
//           SL [32K,40K) ; PMS [40960,41472) ; flag [41472)
__global__ __launch_bounds__(256, 3) void attn_fused(
    const unsigned short* __restrict__ kb_, const unsigned short* __restrict__ vT_,
    float* qbuf, float* pupd, float* pms, int* done, float* slots,
    const short8* __restrict__ wih, const short8* __restrict__ whh,
    const float* __restrict__ bih, const float* __restrict__ bhh,
    const short8* __restrict__ w1p, const float* __restrict__ b1v,
    const short8* __restrict__ w2p, const float* __restrict__ b2v,
    const float* __restrict__ lnsg, const float* __restrict__ lnsb,
    const float* __restrict__ lnmg, const float* __restrict__ lnmb,
    const short8* __restrict__ wqp, float* __restrict__ dout, const int last)
{
  __shared__ __align__(16) char SMEM[41536];
  const int blk = blockIdx.x;
  const int b = blk >> 3, c = blk & 7;
  const int t = threadIdx.x, w = t >> 6, l = t & 63;
  const int m = l & 15;
  float* ls = (float*)SMEM;

  // ---------------- attention partial ----------------
  // q A-fragments straight from qbuf (f32 -> bf16); lanes m>=8 are zero rows.
  short8 aq[8];
  #pragma unroll
  for(int kk = 0; kk < 8; ++kk){
    if(m < 8){
      const float* qp = qbuf + (size_t)b * 2048 + m * 256 + kk * 32 + ((l >> 4) << 3);
      float4 qa = *(const float4*)qp;
      float4 qb = *(const float4*)(qp + 4);
      int4 pv = make_int4((int)pk2(qa.x,qa.y), (int)pk2(qa.z,qa.w),
                          (int)pk2(qb.x,qb.y), (int)pk2(qb.z,qb.w));
      aq[kk] = __builtin_bit_cast(short8, pv);
    } else {
      aq[kk] = (short8){0,0,0,0,0,0,0,0};
    }
  }

  // QK^T: warp w covers n-tiles w*128 .. w*128+127
  const unsigned short* kb = kb_ + ((size_t)b * NN + (size_t)c * CHK) * DD;
  #pragma unroll
  for(int nt = 0; nt < 8; ++nt){
    int nb = w * 128 + nt * 16;
    f32x4 acc = (f32x4){0,0,0,0};
    #pragma unroll
    for(int kk = 0; kk < 8; ++kk){
      short8 bk = *(const short8*)(kb + (size_t)(nb + m) * DD + kk * 32 + ((l >> 4) << 3));
      acc = MFMA(aq[kk], bk, acc);
    }
    if(l < 32){
      int s4 = (l >> 4) * 4;
      #pragma unroll
      for(int j = 0; j < 4; ++j) ls[(s4 + j) * LSP + nb + m] = acc[j];
    }
  }
  __syncthreads();

  // softmax over the 512-chunk per slot
  for(int sh = 0; sh < 2; ++sh){
    int s = w * 2 + sh;
    float* base = ls + s * LSP;
    float4 v0 = *(float4*)(base + l * 4);
    float4 v1 = *(float4*)(base + 256 + l * 4);
    float mx = fmaxf(fmaxf(fmaxf(v0.x,v0.y),fmaxf(v0.z,v0.w)),
                     fmaxf(fmaxf(v1.x,v1.y),fmaxf(v1.z,v1.w)));
    #pragma unroll
    for(int o = 32; o >= 1; o >>= 1) mx = fmaxf(mx, __shfl_xor(mx, o));
    float e0 = __expf(v0.x-mx), e1 = __expf(v0.y-mx), e2 = __expf(v0.z-mx), e3 = __expf(v0.w-mx);
    float e4 = __expf(v1.x-mx), e5 = __expf(v1.y-mx), e6 = __expf(v1.z-mx), e7 = __expf(v1.w-mx);
    float sm = e0+e1+e2+e3+e4+e5+e6+e7;
    #pragma unroll
    for(int o = 32; o >= 1; o >>= 1) sm += __shfl_xor(sm, o);
    *(float4*)(base + l * 4)       = make_float4(e0,e1,e2,e3);
    *(float4*)(base + 256 + l * 4) = make_float4(e4,e5,e6,e7);
    if(l == 0){
      pms[(((size_t)b * 8 + c) * 8 + s) * 2    ] = mx;
      pms[(((size_t)b * 8 + c) * 8 + s) * 2 + 1] = sm;
    }
  }
  __syncthreads();

  // P fragments (lanes m>=8 zero)
  short8 pa[16];
  #pragma unroll
  for(int kk = 0; kk < 16; ++kk){
    if(m < 8){
      const float* pp = ls + m * LSP + kk * 32 + ((l >> 4) << 3);
      int4 pv = make_int4((int)pk2(pp[0],pp[1]), (int)pk2(pp[2],pp[3]),
                          (int)pk2(pp[4],pp[5]), (int)pk2(pp[6],pp[7]));
      pa[kk] = __builtin_bit_cast(short8, pv);
    } else {
      pa[kk] = (short8){0,0,0,0,0,0,0,0};
    }
  }

  // P@V via V^T: warp w covers d 64w .. 64w+63
  const unsigned short* vt = vT_ + ((size_t)b << 20) + (size_t)c * CHK;
  #pragma unroll
  for(int dt = 0; dt < 4; ++dt){
    int d0 = w * 64 + dt * 16;
    f32x4 acc = (f32x4){0,0,0,0};
    #pragma unroll
    for(int kk = 0; kk < 16; ++kk){
      short8 bv = *(const short8*)(vt + ((size_t)(d0 + m) << 12) + kk * 32 + ((l >> 4) << 3));
      acc = MFMA(pa[kk], bv, acc);
    }
    if(l < 32){
      int s4 = (l >> 4) * 4;
      #pragma unroll
      for(int j = 0; j < 4; ++j)
        pupd[((size_t)b * 8 + c) * 2048 + (s4 + j) * 256 + d0 + m] = acc[j];
    }
  }

  // ---------------- completion counter ----------------
  __threadfence();
  __syncthreads();
  int* flag = (int*)(SMEM + 41472);
  if(t == 0){
    int old = atomicAdd(&done[b], 1);
    *flag = (old == 7) ? 1 : 0;
    if(old == 7) atomicExch(&done[b], 0);
  }
  __syncthreads();
  if(*flag == 0) return;
  __threadfence();   // acquire: other chunks' pupd/pms now visible

  // ---------------- update tail (one block per batch) ----------------
  unsigned short* A1 = (unsigned short*)SMEM;
  unsigned short* A2 = (unsigned short*)(SMEM + 8192);
  unsigned short* A3 = (unsigned short*)(SMEM + 16384);
  float* GR  = (float*)SMEM;
  float* GZ  = (float*)(SMEM + 8192);
  float* GXN = (float*)(SMEM + 16384);
  float* GHN = (float*)(SMEM + 24576);
  float* SL  = (float*)(SMEM + 32768);
  float* PMS = (float*)(SMEM + 40960);

  if(t < 128) PMS[t] = pms[(size_t)b * 128 + t];
  __syncthreads();

  float upd[8], pv[8];
  #pragma unroll
  for(int s = 0; s < 8; ++s){
    float mx = -1e30f;
    #pragma unroll
    for(int cc = 0; cc < 8; ++cc) mx = fmaxf(mx, PMS[(cc * 8 + s) * 2]);
    float Z = 0.f, u = 0.f;
    #pragma unroll
    for(int cc = 0; cc < 8; ++cc){
      float e = __expf(PMS[(cc * 8 + s) * 2] - mx);
      Z += e * PMS[(cc * 8 + s) * 2 + 1];
      u += e * pupd[((size_t)b * 8 + cc) * 2048 + s * 256 + t];
    }
    upd[s] = u / Z;
    pv[s]  = slots[(size_t)b * 2048 + s * 256 + t];
  }
  __syncthreads();  // ls region fully dead before A1/A2 writes
  #pragma unroll
  for(int s = 0; s < 8; ++s){
    int byte = s * 512 + ((t * 2) ^ ((s & 7) << 4));
    *(unsigned short*)((char*)A1 + byte) = f2bf(upd[s]);
    *(unsigned short*)((char*)A2 + byte) = f2bf(pv[s]);
  }
  __syncthreads();

  {
    short8 a1f[8], a2f[8];
    #pragma unroll
    for(int kk = 0; kk < 8; ++kk){
      int ab = m * 512 + (((kk * 64) + ((l >> 4) << 4)) ^ ((m & 7) << 4));
      a1f[kk] = *(const short8*)((const char*)A1 + ab);
      a2f[kk] = *(const short8*)((const char*)A2 + ab);
    }
    __syncthreads();  // frag regs loaded; gates may now overwrite A1/A2/A3 region
    #pragma unroll
    for(int i = 0; i < 12; ++i){
      int et = w + i * 4;
      f32x4 c1 = (f32x4){0,0,0,0}, c2 = (f32x4){0,0,0,0};
      #pragma unroll
      for(int kk = 0; kk < 8; ++kk){
        c1 = MFMA(a1f[kk], wih[((kk * 48 + et) << 6) + l], c1);
        c2 = MFMA(a2f[kk], whh[((kk * 48 + et) << 6) + l], c2);
      }
      int e = et * 16 + (l & 15);
      float xb = bih[e], hb = bhh[e];
      #pragma unroll
      for(int j = 0; j < 4; ++j){
        int s = ((l >> 4) << 2) + j;
        if(s < 8){
          float x = c1[j] + xb, h = c2[j] + hb;
          if(et < 16)      GR[s * 256 + e      ] = 1.f/(1.f + __expf(-(x + h)));
          else if(et < 32) GZ[s * 256 + (e-256)] = 1.f/(1.f + __expf(-(x + h)));
          else { GXN[s * 256 + (e-512)] = x; GHN[s * 256 + (e-512)] = h; }
        }
      }
    }
  }
  __syncthreads();

  #pragma unroll
  for(int s = 0; s < 8; ++s){
    int idx = s * 256 + t;
    float r = GR[idx], z = GZ[idx], xn = GXN[idx], hn = GHN[idx];
    float nn = tanhf(xn + r * hn);
    SL[idx] = (1.f - z) * nn + z * pv[s];
  }
  __syncthreads();

  // LN_mlp -> A1 (bf16) [0,8K)  (gates dead)
  {
    float4 g4 = ((const float4*)lnmg)[l], bb4 = ((const float4*)lnmb)[l];
    for(int sh = 0; sh < 2; ++sh){
      int s = w * 2 + sh;
      float4 x4 = ((const float4*)(SL + s * 256))[l];
      float s1 = x4.x + x4.y + x4.z + x4.w;
      float s2 = x4.x*x4.x + x4.y*x4.y + x4.z*x4.z + x4.w*x4.w;
      #pragma unroll
      for(int o = 32; o >= 1; o >>= 1){ s1 += __shfl_xor(s1, o); s2 += __shfl_xor(s2, o); }
      float mean = s1 * (1.0f/256.0f);
      float inv  = rsqrtf(s2 * (1.0f/256.0f) - mean*mean + 1e-5f);
      float y0 = (x4.x-mean)*inv*g4.x + bb4.x;
      float y1 = (x4.y-mean)*inv*g4.y + bb4.y;
      float y2 = (x4.z-mean)*inv*g4.z + bb4.z;
      float y3 = (x4.w-mean)*inv*g4.w + bb4.w;
      int byte = s * 512 + ((l * 8) ^ ((s & 7) << 4));
      *(uint2*)((char*)A1 + byte) = make_uint2(pk2(y0,y1), pk2(y2,y3));
    }
  }
  __syncthreads();

  // MLP1 -> h (bf16, relu) into A3 [16K,32K)
  {
    short8 af[8];
    #pragma unroll
    for(int kk = 0; kk < 8; ++kk){
      int ab = m * 512 + (((kk * 64) + ((l >> 4) << 4)) ^ ((m & 7) << 4));
      af[kk] = *(const short8*)((const char*)A1 + ab);
    }
    #pragma unroll
    for(int i = 0; i < 8; ++i){
      int et = w + i * 4;
      f32x4 cc = (f32x4){0,0,0,0};
      #pragma unroll
      for(int kk = 0; kk < 8; ++kk) cc = MFMA(af[kk], w1p[((kk * 32 + et) << 6) + l], cc);
      int e = et * 16 + (l & 15);
      float bb = b1v[e];
      #pragma unroll
      for(int j = 0; j < 4; ++j){
        int s = ((l >> 4) << 2) + j;
        if(s < 8){
          float h = fmaxf(cc[j] + bb, 0.f);
          int byte = s * 1024 + ((e * 2) ^ ((s & 7) << 4));
          *(unsigned short*)((char*)A3 + byte) = f2bf(h);
        }
      }
    }
  }
  __syncthreads();

  // MLP2 + residual -> OUT (f32) at [8K,16K)
  float* OUT = (float*)(SMEM + 8192);
  {
    short8 af[16];
    #pragma unroll
    for(int kk = 0; kk < 16; ++kk){
      int ab = m * 1024 + (((kk * 64) + ((l >> 4) << 4)) ^ ((m & 7) << 4));
      af[kk] = *(const short8*)((const char*)A3 + ab);
    }
    __syncthreads();  // frags in regs; OUT may overwrite GZ region
    #pragma unroll
    for(int i = 0; i < 4; ++i){
      int et = w + i * 4;
      f32x4 cc = (f32x4){0,0,0,0};
      #pragma unroll
      for(int kk = 0; kk < 16; ++kk) cc = MFMA(af[kk], w2p[((kk * 16 + et) << 6) + l], cc);
      int e = et * 16 + (l & 15);
      float bb = b2v[e];
      #pragma unroll
      for(int j = 0; j < 4; ++j){
        int s = ((l >> 4) << 2) + j;
        if(s < 8) OUT[s * 256 + e] = SL[s * 256 + e] + cc[j] + bb;
      }
    }
  }
  __syncthreads();

  for(int i = t; i < 2048; i += 256){
    float v = OUT[i];
    slots[(size_t)b * 2048 + i] = v;
    if(last) dout[(size_t)b * 2048 + i] = v;
  }
  // LN_slots -> A1 (bf16) [0,8K)
  {
    float4 g4 = ((const float4*)lnsg)[l], bb4 = ((const float4*)lnsb)[l];
    for(int sh = 0; sh < 2; ++sh){
      int s = w * 2 + sh;
      float4 x4 = ((const float4*)(OUT + s * 256))[l];
      float s1 = x4.x + x4.y + x4.z + x4.w;
      float s2 = x4.x*x4.x + x4.y*x4.y + x4.z*x4.z + x4.w*x4.w;
      #pragma unroll
      for(int o = 32; o >= 1; o >>= 1){ s1 += __shfl_xor(s1, o); s2 += __shfl_xor(s2, o); }
      float mean = s1 * (1.0f/256.0f);
      float inv  = rsqrtf(s2 * (1.0f/256.0f) - mean*mean + 1e-5f);
      float y0 = (x4.x-mean)*inv*g4.x + bb4.x;
      float y1 = (x4.y-mean)*inv*g4.y + bb4.y;
      float y2 = (x4.z-mean)*inv*g4.z + bb4.z;
      float y3 = (x4.w-mean)*inv*g4.w + bb4.w;
      int byte = s * 512 + ((l * 8) ^ ((s & 7) << 4));
      *(uint2*)((char*)A1 + byte) = make_uint2(pk2(y0,y1), pk2(y2,y3));
    }
  }
  __syncthreads();
  // next q
  {
    short8 af[8];
    #pragma unroll
    for(int kk = 0; kk < 8; ++kk){
      int ab = m * 512 + (((kk * 64) + ((l >> 4) << 4)) ^ ((m & 7) << 4));
      af[kk] = *(const short8*)((const char*)A1 + ab);
    }
    #pragma unroll
    for(int i = 0; i < 4; ++i){
      int et = w + i * 4;
      f32x4 cc = (f32x4){0,0,0,0};
      #pragma unroll
      for(int kk = 0; kk < 8; ++kk) cc = MFMA(af[kk], wqp[((kk * 16 + et) << 6) + l], cc);
      int e = et * 16 + (l & 15);
      #pragma unroll
      for(int j = 0; j < 4; ++j){
        int s = ((l >> 4) << 2) + j;
        if(s < 8) qbuf[(size_t)b * 2048 + s * 256 + e] = cc[j] * 0.0625f;
      }
    }
  }
}

extern "C" void kernel_launch(void* const* d_in, const int* in_sizes, int n_in,
                              void* d_out, int out_size, void* d_ws, size_t ws_size,
                              hipStream_t stream)
{
  const float* inp   = (const float*)d_in[0];
  const float* noise = (const float*)d_in[1];
  const float* mu    = (const float*)d_in[2];
  const float* lsg   = (const float*)d_in[3];
  const float* lngi  = (const float*)d_in[4];
  const float* lnbi  = (const float*)d_in[5];
  const float* lngs  = (const float*)d_in[6];
  const float* lnbs  = (const float*)d_in[7];
  const float* lngm  = (const float*)d_in[8];
  const float* lnbm  = (const float*)d_in[9];
  const float* Wq    = (const float*)d_in[10];
  const float* Wk    = (const float*)d_in[11];
  const float* Wv    = (const float*)d_in[12];
  const float* Wih   = (const float*)d_in[13];
  const float* Whh   = (const float*)d_in[14];
  const float* bih   = (const float*)d_in[15];
  const float* bhh   = (const float*)d_in[16];
  const float* W1    = (const float*)d_in[17];
  const float* b1    = (const float*)d_in[18];
  const float* W2    = (const float*)d_in[19];
  const float* b2    = (const float*)d_in[20];
  float* dout = (float*)d_out;

  char* ws = (char*)d_ws;
  size_t off = 0;
  unsigned short* kb  = (unsigned short*)(ws + off); off += (size_t)BB*NN*DD*2;
  unsigned short* vT  = (unsigned short*)(ws + off); off += (size_t)BB*NN*DD*2;
  short8* wqp = (short8*)(ws + off); off += (size_t)256*256*2;
  short8* wkp = (short8*)(ws + off); off += (size_t)256*256*2;
  short8* wvp = (short8*)(ws + off); off += (size_t)256*256*2;
  short8* wihp= (short8*)(ws + off); off += (size_t)768*256*2;
  short8* whhp= (short8*)(ws + off); off += (size_t)768*256*2;
  short8* w1p = (short8*)(ws + off); off += (size_t)512*256*2;
  short8* w2p = (short8*)(ws + off); off += (size_t)256*512*2;
  float* qbuf = (float*)(ws + off); off += (size_t)512*256*4;
  float* slots= (float*)(ws + off); off += (size_t)512*256*4;
  float* pupd = (float*)(ws + off); off += (size_t)64*8*8*256*4;
  float* pms  = (float*)(ws + off); off += (size_t)64*8*8*2*4;
  int*   done = (int*)(ws + off);   off += (size_t)BB*4;

  PackDesc pd;
  const float* srcs[7] = {Wq, Wk, Wv, Wih, Whh, W1, W2};
  unsigned short* dsts[7] = {(unsigned short*)wqp, (unsigned short*)wkp, (unsigned short*)wvp,
                             (unsigned short*)wihp, (unsigned short*)whhp,
                             (unsigned short*)w1p, (unsigned short*)w2p};
  int ets[7] = {16, 16, 16, 48, 48, 32, 16};
  int ks [7] = {256, 256, 256, 256, 256, 256, 512};
  int cum = 0;
  for(int i = 0; i < 7; ++i){
    pd.src[i] = srcs[i]; pd.dst[i] = dsts[i]; pd.ET[i] = ets[i]; pd.K[i] = ks[i];
    pd.blkStart[i] = cum;
    cum += (ets[i] * 16 * ks[i] + 255) / 256;
  }
  pd.blkStart[7] = cum;
  pack_all_kernel<<<cum, 256, 0, stream>>>(pd, done);

  proj_kernel<<<4096, 256, 0, stream>>>(inp, lngi, lnbi, wkp, wvp, kb, vT);
  init_kernel<<<64, 256, 0, stream>>>(noise, mu, lsg, lngs, lnbs, wqp, slots, qbuf);

  for(int it = 0; it < 3; ++it){
    attn_fused<<<512, 256, 0, stream>>>(kb, vT, qbuf, pupd, pms, done, slots,
        wihp, whhp, bih, bhh, w1p, b1, w2p, b2,
        lngs, lnbs, lngm, lnbm, wqp, dout, (it == 2) ? 1 : 0);
  }
}

// Round 7
// 422.130 us; speedup vs baseline: 1.8946x; 1.8946x over previous
//
#include <hip/hip_runtime.h>

// Slot attention, MI355X. B=64,N=4096,S=8,D=256,H=512,ITERS=3.
#define BB 64
#define NN 4096
#define SS 8
#define DD 256
#define HH 512
#define NCH 8
#define CHK 512
#define LSP 516  // padded row stride (f32) for logits LDS

typedef __attribute__((ext_vector_type(4))) float f32x4;
typedef __attribute__((ext_vector_type(8))) short short8;
typedef __attribute__((ext_vector_type(8))) __bf16 bf16x8;

static __device__ __forceinline__ f32x4 MFMA(short8 a, short8 b, f32x4 c){
  return __builtin_amdgcn_mfma_f32_16x16x32_bf16(
      __builtin_bit_cast(bf16x8, a), __builtin_bit_cast(bf16x8, b), c, 0, 0, 0);
}

static __device__ __forceinline__ unsigned short f2bf(float f){
  unsigned int x = __builtin_bit_cast(unsigned int, f);
  x += 0x7FFFu + ((x >> 16) & 1u);
  return (unsigned short)(x >> 16);
}

static __device__ __forceinline__ unsigned int pk2(float a, float b){
  return (unsigned int)f2bf(a) | ((unsigned int)f2bf(b) << 16);
}

// ---- merged weight pack: W(E=ET*16, K) fp32 row-major -> bf16 MFMA fragments
struct PackDesc {
  const float* src[7];
  unsigned short* dst[7];
  int ET[7];
  int K[7];
  int blkStart[8];
};

__global__ void pack_all_kernel(PackDesc pd){
  int blk = blockIdx.x;
  int seg = 0;
  #pragma unroll
  for(int i = 1; i < 7; ++i) if(blk >= pd.blkStart[i]) seg = i;
  int tid = (blk - pd.blkStart[seg]) * 256 + threadIdx.x;
  int ET = pd.ET[seg], K = pd.K[seg];
  if(tid >= ET * 16 * K) return;
  int i    = tid & 7;
  int lane = (tid >> 3) & 63;
  int rest = tid >> 9;
  int et = rest % ET;
  int kk = rest / ET;
  int row = et * 16 + (lane & 15);
  int col = kk * 32 + ((lane >> 4) << 3) + i;
  pd.dst[seg][tid] = f2bf(pd.src[seg][(size_t)row * K + col]);
}

// LN(inputs) -> x(bf16, LDS, swizzled) -> K row-major ; V^T [b][d][n].
// A-fragments are re-read from LDS inside the MFMA loops (no persistent af[] regs)
// to cut VGPR pressure and raise occupancy; LDS bandwidth absorbs the re-reads.
__global__ __launch_bounds__(256, 2) void proj_kernel(
    const float* __restrict__ inp, const float* __restrict__ g, const float* __restrict__ bta,
    const short8* __restrict__ wkp, const short8* __restrict__ wvp,
    unsigned short* __restrict__ kout, unsigned short* __restrict__ vT)
{
  __shared__ unsigned short xs[64 * 256];      // 32 KB LN'd input tile
  __shared__ unsigned short vstage[4][1024];   // 8 KB per-warp V^T staging
  const int t = threadIdx.x, w = t >> 6, l = t & 63;
  const size_t row0 = (size_t)blockIdx.x * 64;
  const int b = (int)(row0 >> 12);
  const int n_base = (int)(row0 & 4095);
  const int li = l & 15, lg = l >> 4;

  // LN: 16 lanes per row, 4 rows in flight per warp
  {
    float4 gg[4], bb[4];
    #pragma unroll
    for(int q = 0; q < 4; ++q){
      gg[q] = ((const float4*)g)[li + q * 16];
      bb[q] = ((const float4*)bta)[li + q * 16];
    }
    #pragma unroll
    for(int rr = 0; rr < 4; ++rr){
      int r = w * 16 + rr * 4 + lg;
      const float4* rp = (const float4*)(inp + (row0 + r) * DD);
      float4 x[4];
      #pragma unroll
      for(int q = 0; q < 4; ++q) x[q] = rp[li + q * 16];
      float s1 = 0.f, s2 = 0.f;
      #pragma unroll
      for(int q = 0; q < 4; ++q){
        s1 += x[q].x + x[q].y + x[q].z + x[q].w;
        s2 += x[q].x*x[q].x + x[q].y*x[q].y + x[q].z*x[q].z + x[q].w*x[q].w;
      }
      #pragma unroll
      for(int o = 8; o >= 1; o >>= 1){ s1 += __shfl_xor(s1, o); s2 += __shfl_xor(s2, o); }
      float mean = s1 * (1.0f/256.0f);
      float inv  = rsqrtf(s2 * (1.0f/256.0f) - mean*mean + 1e-5f);
      #pragma unroll
      for(int q = 0; q < 4; ++q){
        float y0 = (x[q].x-mean)*inv*gg[q].x + bb[q].x;
        float y1 = (x[q].y-mean)*inv*gg[q].y + bb[q].y;
        float y2 = (x[q].z-mean)*inv*gg[q].z + bb[q].z;
        float y3 = (x[q].w-mean)*inv*gg[q].w + bb[q].w;
        int byte = r * 512 + ((q * 128 + li * 8) ^ ((r & 7) << 4));
        *(uint2*)((char*)xs + byte) = make_uint2(pk2(y0,y1), pk2(y2,y3));
      }
    }
  }
  __syncthreads();

  const int et0 = w * 4;
  // K: swapped operands => lane holds 4 consecutive d at fixed n; direct 8B stores.
  #pragma unroll
  for(int el = 0; el < 4; ++el){
    const int et = et0 + el;
    short8 wb[8];
    #pragma unroll
    for(int kk = 0; kk < 8; ++kk) wb[kk] = wkp[((kk * 16 + et) << 6) + l];
    #pragma unroll
    for(int rg = 0; rg < 4; ++rg){
      const int r = rg * 16 + li;
      f32x4 a = (f32x4){0,0,0,0};
      #pragma unroll
      for(int kk = 0; kk < 8; ++kk){
        int ab = r * 512 + (((kk * 64) + (lg << 4)) ^ ((r & 7) << 4));
        short8 afr = *(const short8*)((const char*)xs + ab);
        a = MFMA(wb[kk], afr, a);
      }
      size_t row = row0 + rg * 16 + li;
      int colb = et * 16 + (lg << 2);
      *(uint2*)(kout + row * DD + colb) = make_uint2(pk2(a[0],a[1]), pk2(a[2],a[3]));
    }
  }
  // V: direct operands => lane holds 4 consecutive n at fixed e. Stage per-warp in LDS,
  // then store V^T rows as coalesced 16B bursts.
  #pragma unroll
  for(int el = 0; el < 4; ++el){
    const int et = et0 + el;
    short8 wb[8];
    #pragma unroll
    for(int kk = 0; kk < 8; ++kk) wb[kk] = wvp[((kk * 16 + et) << 6) + l];
    char* vs = (char*)&vstage[w][0];
    #pragma unroll
    for(int rg = 0; rg < 4; ++rg){
      const int r = rg * 16 + li;
      f32x4 a = (f32x4){0,0,0,0};
      #pragma unroll
      for(int kk = 0; kk < 8; ++kk){
        int ab = r * 512 + (((kk * 64) + (lg << 4)) ^ ((r & 7) << 4));
        short8 afr = *(const short8*)((const char*)xs + ab);
        a = MFMA(afr, wb[kk], a);
      }
      int nloc = rg * 16 + (lg << 2);
      int byte = li * 128 + ((nloc * 2) ^ ((li & 7) << 4));
      *(uint2*)(vs + byte) = make_uint2(pk2(a[0],a[1]), pk2(a[2],a[3]));
    }
    asm volatile("s_waitcnt lgkmcnt(0)" ::: "memory");
    #pragma unroll
    for(int u = 0; u < 2; ++u){
      int dl = u * 8 + (l >> 3);
      int byte = dl * 128 + (((l & 7) * 16) ^ ((dl & 7) << 4));
      uint4 vv = *(uint4*)(vs + byte);
      int d = et * 16 + dl;
      *(uint4*)(vT + ((size_t)(b * 256 + d) << 12) + n_base + (l & 7) * 8) = vv;
    }
    asm volatile("" ::: "memory");
  }
}

// slots0 = mu + exp(log_sigma)*noise ; q = LN_slots(slots0)@Wq^T * D^-0.5
__global__ __launch_bounds__(256, 1) void init_kernel(
    const float* __restrict__ noise, const float* __restrict__ mu, const float* __restrict__ lsg,
    const float* __restrict__ lng, const float* __restrict__ lnb,
    const short8* __restrict__ wqp, float* __restrict__ slots, float* __restrict__ qbuf)
{
  const int b = blockIdx.x, t = threadIdx.x, w = t >> 6, l = t & 63;
  __shared__ float SLN[SS * DD];
  __shared__ unsigned short A1[16 * DD];
  float muv = mu[t];
  float sgv = __expf(lsg[t]);
  #pragma unroll
  for(int s = 0; s < SS; ++s){
    float v = muv + sgv * noise[(size_t)b * 2048 + s * 256 + t];
    slots[(size_t)b * 2048 + s * 256 + t] = v;
    SLN[s * 256 + t] = v;
  }
  __syncthreads();
  float4 g4 = ((const float4*)lng)[l], bb4 = ((const float4*)lnb)[l];
  for(int sh = 0; sh < 2; ++sh){
    int s = w * 2 + sh;
    float4 x4 = ((const float4*)(SLN + s * 256))[l];
    float s1 = x4.x + x4.y + x4.z + x4.w;
    float s2 = x4.x*x4.x + x4.y*x4.y + x4.z*x4.z + x4.w*x4.w;
    #pragma unroll
    for(int o = 32; o >= 1; o >>= 1){ s1 += __shfl_xor(s1, o); s2 += __shfl_xor(s2, o); }
    float mean = s1 * (1.0f/256.0f);
    float inv  = rsqrtf(s2 * (1.0f/256.0f) - mean*mean + 1e-5f);
    float y0 = (x4.x-mean)*inv*g4.x + bb4.x;
    float y1 = (x4.y-mean)*inv*g4.y + bb4.y;
    float y2 = (x4.z-mean)*inv*g4.z + bb4.z;
    float y3 = (x4.w-mean)*inv*g4.w + bb4.w;
    int byte = s * 512 + ((l * 8) ^ ((s & 7) << 4));
    *(uint2*)((char*)A1 + byte) = make_uint2(pk2(y0,y1), pk2(y2,y3));
  }
  __syncthreads();
  const int m = l & 15;
  short8 af[8];
  #pragma unroll
  for(int kk = 0; kk < 8; ++kk){
    int ab = m * 512 + (((kk * 64) + ((l >> 4) << 4)) ^ ((m & 7) << 4));
    af[kk] = *(const short8*)((const char*)A1 + ab);
  }
  #pragma unroll
  for(int i = 0; i < 4; ++i){
    int et = w + i * 4;
    f32x4 c = (f32x4){0,0,0,0};
    #pragma unroll
    for(int kk = 0; kk < 8; ++kk) c = MFMA(af[kk], wqp[((kk * 16 + et) << 6) + l], c);
    int e = et * 16 + (l & 15);
    #pragma unroll
    for(int j = 0; j < 4; ++j){
      int s = ((l >> 4) << 2) + j;
      if(s < 8) qbuf[(size_t)b * 2048 + s * 256 + e] = c[j] * 0.0625f;
    }
  }
}

// MFMA flash-attention partials: QK^T (A=q from qbuf, B=K row-major), softmax, P@V (A=P, B=V^T).
__global__ __launch_bounds__(256, 3) void attn_kernel(
    const unsigned short* __restrict__ kb_, const unsigned short* __restrict__ vT_,
    const float* __restrict__ qbuf, float* __restrict__ pupd, float* __restrict__ pms)
{
  const int blk = blockIdx.x;
  const int b = blk >> 3, c = blk & 7;
  const int t = threadIdx.x, w = t >> 6, l = t & 63;
  __shared__ float ls[8 * LSP];   // 16.5 KB: exp(logits) rows 0..7

  const int m = l & 15;
  // q A-fragments straight from qbuf (f32 -> bf16); lanes m>=8 are zero rows.
  short8 aq[8];
  #pragma unroll
  for(int kk = 0; kk < 8; ++kk){
    if(m < 8){
      const float* qp = qbuf + (size_t)b * 2048 + m * 256 + kk * 32 + ((l >> 4) << 3);
      float4 qa = *(const float4*)qp;
      float4 qb = *(const float4*)(qp + 4);
      int4 pv = make_int4((int)pk2(qa.x,qa.y), (int)pk2(qa.z,qa.w),
                          (int)pk2(qb.x,qb.y), (int)pk2(qb.z,qb.w));
      aq[kk] = __builtin_bit_cast(short8, pv);
    } else {
      aq[kk] = (short8){0,0,0,0,0,0,0,0};
    }
  }

  // QK^T: warp w covers n-tiles w*128 .. w*128+127
  const unsigned short* kb = kb_ + ((size_t)b * NN + (size_t)c * CHK) * DD;
  #pragma unroll
  for(int nt = 0; nt < 8; ++nt){
    int nb = w * 128 + nt * 16;
    f32x4 acc = (f32x4){0,0,0,0};
    #pragma unroll
    for(int kk = 0; kk < 8; ++kk){
      short8 bk = *(const short8*)(kb + (size_t)(nb + m) * DD + kk * 32 + ((l >> 4) << 3));
      acc = MFMA(aq[kk], bk, acc);
    }
    if(l < 32){
      int s4 = (l >> 4) * 4;
      #pragma unroll
      for(int j = 0; j < 4; ++j) ls[(s4 + j) * LSP + nb + m] = acc[j];
    }
  }
  __syncthreads();

  // softmax over the 512-chunk per slot (warp w handles slots 2w, 2w+1)
  for(int sh = 0; sh < 2; ++sh){
    int s = w * 2 + sh;
    float* base = ls + s * LSP;
    float4 v0 = *(float4*)(base + l * 4);
    float4 v1 = *(float4*)(base + 256 + l * 4);
    float mx = fmaxf(fmaxf(fmaxf(v0.x,v0.y),fmaxf(v0.z,v0.w)),
                     fmaxf(fmaxf(v1.x,v1.y),fmaxf(v1.z,v1.w)));
    #pragma unroll
    for(int o = 32; o >= 1; o >>= 1) mx = fmaxf(mx, __shfl_xor(mx, o));
    float e0 = __expf(v0.x-mx), e1 = __expf(v0.y-mx), e2 = __expf(v0.z-mx), e3 = __expf(v0.w-mx);
    float e4 = __expf(v1.x-mx), e5 = __expf(v1.y-mx), e6 = __expf(v1.z-mx), e7 = __expf(v1.w-mx);
    float sm = e0+e1+e2+e3+e4+e5+e6+e7;
    #pragma unroll
    for(int o = 32; o >= 1; o >>= 1) sm += __shfl_xor(sm, o);
    *(float4*)(base + l * 4)       = make_float4(e0,e1,e2,e3);
    *(float4*)(base + 256 + l * 4) = make_float4(e4,e5,e6,e7);
    if(l == 0){
      pms[(((size_t)b * 8 + c) * 8 + s) * 2    ] = mx;
      pms[(((size_t)b * 8 + c) * 8 + s) * 2 + 1] = sm;
    }
  }
  __syncthreads();

  // P fragments (lanes m>=8 are zero rows)
  short8 pa[16];
  #pragma unroll
  for(int kk = 0; kk < 16; ++kk){
    if(m < 8){
      const float* pp = ls + m * LSP + kk * 32 + ((l >> 4) << 3);
      int4 pv = make_int4((int)pk2(pp[0],pp[1]), (int)pk2(pp[2],pp[3]),
                          (int)pk2(pp[4],pp[5]), (int)pk2(pp[6],pp[7]));
      pa[kk] = __builtin_bit_cast(short8, pv);
    } else {
      pa[kk] = (short8){0,0,0,0,0,0,0,0};
    }
  }

  // P@V via V^T: warp w covers d 64w .. 64w+63
  const unsigned short* vt = vT_ + ((size_t)b << 20) + (size_t)c * CHK;
  #pragma unroll
  for(int dt = 0; dt < 4; ++dt){
    int d0 = w * 64 + dt * 16;
    f32x4 acc = (f32x4){0,0,0,0};
    #pragma unroll
    for(int kk = 0; kk < 16; ++kk){
      short8 bv = *(const short8*)(vt + ((size_t)(d0 + m) << 12) + kk * 32 + ((l >> 4) << 3));
      acc = MFMA(pa[kk], bv, acc);
    }
    if(l < 32){
      int s4 = (l >> 4) * 4;
      #pragma unroll
      for(int j = 0; j < 4; ++j)
        pupd[((size_t)b * 8 + c) * 2048 + (s4 + j) * 256 + d0 + m] = acc[j];
    }
  }
}

// Combine partials -> upd ; GRU ; residual MLP ; write slots (+dout) ; LN_slots ; next q
// 512 threads / 8 warps.
__global__ __launch_bounds__(512, 1) void update_kernel(
    const float* __restrict__ pupd, const float* __restrict__ pms,
    float* __restrict__ slots, float* __restrict__ qbuf,
    const short8* __restrict__ wih, const short8* __restrict__ whh,
    const float* __restrict__ bih, const float* __restrict__ bhh,
    const short8* __restrict__ w1p, const float* __restrict__ b1v,
    const short8* __restrict__ w2p, const float* __restrict__ b2v,
    const float* __restrict__ lnsg, const float* __restrict__ lnsb,
    const float* __restrict__ lnmg, const float* __restrict__ lnmb,
    const short8* __restrict__ wqp,
    float* __restrict__ dout, const int last)
{
  const int b = blockIdx.x, t = threadIdx.x, w = t >> 6, l = t & 63;
  __shared__ unsigned short A1[16 * 256];
  __shared__ unsigned short A2[16 * 256];
  __shared__ unsigned short A3[16 * 512];
  __shared__ float GR[8 * 256], GZ[8 * 256], GXN[8 * 256], GHN[8 * 256];
  __shared__ float SL[8 * 256];
  __shared__ float PMS[128];

  if(t < 128) PMS[t] = pms[(size_t)b * 128 + t];
  __syncthreads();

  const int col = t & 255, sg = t >> 8;
  float upd[4], pv[4];
  #pragma unroll
  for(int ss = 0; ss < 4; ++ss){
    int s = sg * 4 + ss;
    float mx = -1e30f;
    #pragma unroll
    for(int cc = 0; cc < 8; ++cc) mx = fmaxf(mx, PMS[(cc * 8 + s) * 2]);
    float Z = 0.f, u = 0.f;
    #pragma unroll
    for(int cc = 0; cc < 8; ++cc){
      float e = __expf(PMS[(cc * 8 + s) * 2] - mx);
      Z += e * PMS[(cc * 8 + s) * 2 + 1];
      u += e * pupd[((size_t)b * 8 + cc) * 2048 + s * 256 + col];
    }
    upd[ss] = u / Z;
    pv[ss]  = slots[(size_t)b * 2048 + s * 256 + col];
  }
  #pragma unroll
  for(int ss = 0; ss < 4; ++ss){
    int s = sg * 4 + ss;
    int byte = s * 512 + ((col * 2) ^ ((s & 7) << 4));
    *(unsigned short*)((char*)A1 + byte) = f2bf(upd[ss]);
    *(unsigned short*)((char*)A2 + byte) = f2bf(pv[ss]);
  }
  __syncthreads();

  {
    const int m = l & 15;
    short8 a1f[8], a2f[8];
    #pragma unroll
    for(int kk = 0; kk < 8; ++kk){
      int ab = m * 512 + (((kk * 64) + ((l >> 4) << 4)) ^ ((m & 7) << 4));
      a1f[kk] = *(const short8*)((const char*)A1 + ab);
      a2f[kk] = *(const short8*)((const char*)A2 + ab);
    }
    #pragma unroll
    for(int i = 0; i < 6; ++i){
      int et = w + i * 8;
      f32x4 c1 = (f32x4){0,0,0,0}, c2 = (f32x4){0,0,0,0};
      #pragma unroll
      for(int kk = 0; kk < 8; ++kk){
        c1 = MFMA(a1f[kk], wih[((kk * 48 + et) << 6) + l], c1);
        c2 = MFMA(a2f[kk], whh[((kk * 48 + et) << 6) + l], c2);
      }
      int e = et * 16 + (l & 15);
      float xb = bih[e], hb = bhh[e];
      #pragma unroll
      for(int j = 0; j < 4; ++j){
        int s = ((l >> 4) << 2) + j;
        if(s < 8){
          float x = c1[j] + xb, h = c2[j] + hb;
          if(et < 16)      GR[s * 256 + e      ] = 1.f/(1.f + __expf(-(x + h)));
          else if(et < 32) GZ[s * 256 + (e-256)] = 1.f/(1.f + __expf(-(x + h)));
          else { GXN[s * 256 + (e-512)] = x; GHN[s * 256 + (e-512)] = h; }
        }
      }
    }
  }
  __syncthreads();

  #pragma unroll
  for(int ss = 0; ss < 4; ++ss){
    int s = sg * 4 + ss, idx = s * 256 + col;
    float r = GR[idx], z = GZ[idx], xn = GXN[idx], hn = GHN[idx];
    float nn = tanhf(xn + r * hn);
    SL[idx] = (1.f - z) * nn + z * pv[ss];
  }
  __syncthreads();

  {
    float4 g4 = ((const float4*)lnmg)[l], bb4 = ((const float4*)lnmb)[l];
    int s = w;
    float4 x4 = ((const float4*)(SL + s * 256))[l];
    float s1 = x4.x + x4.y + x4.z + x4.w;
    float s2 = x4.x*x4.x + x4.y*x4.y + x4.z*x4.z + x4.w*x4.w;
    #pragma unroll
    for(int o = 32; o >= 1; o >>= 1){ s1 += __shfl_xor(s1, o); s2 += __shfl_xor(s2, o); }
    float mean = s1 * (1.0f/256.0f);
    float inv  = rsqrtf(s2 * (1.0f/256.0f) - mean*mean + 1e-5f);
    float y0 = (x4.x-mean)*inv*g4.x + bb4.x;
    float y1 = (x4.y-mean)*inv*g4.y + bb4.y;
    float y2 = (x4.z-mean)*inv*g4.z + bb4.z;
    float y3 = (x4.w-mean)*inv*g4.w + bb4.w;
    int byte = s * 512 + ((l * 8) ^ ((s & 7) << 4));
    *(uint2*)((char*)A1 + byte) = make_uint2(pk2(y0,y1), pk2(y2,y3));
  }
  __syncthreads();

  {
    const int m = l & 15;
    short8 af[8];
    #pragma unroll
    for(int kk = 0; kk < 8; ++kk){
      int ab = m * 512 + (((kk * 64) + ((l >> 4) << 4)) ^ ((m & 7) << 4));
      af[kk] = *(const short8*)((const char*)A1 + ab);
    }
    #pragma unroll
    for(int i = 0; i < 4; ++i){
      int et = w + i * 8;
      f32x4 c = (f32x4){0,0,0,0};
      #pragma unroll
      for(int kk = 0; kk < 8; ++kk) c = MFMA(af[kk], w1p[((kk * 32 + et) << 6) + l], c);
      int e = et * 16 + (l & 15);
      float bb = b1v[e];
      #pragma unroll
      for(int j = 0; j < 4; ++j){
        int s = ((l >> 4) << 2) + j;
        if(s < 8){
          float h = fmaxf(c[j] + bb, 0.f);
          int byte = s * 1024 + ((e * 2) ^ ((s & 7) << 4));
          *(unsigned short*)((char*)A3 + byte) = f2bf(h);
        }
      }
    }
  }
  __syncthreads();

  {
    const int m = l & 15;
    short8 af[16];
    #pragma unroll
    for(int kk = 0; kk < 16; ++kk){
      int ab = m * 1024 + (((kk * 64) + ((l >> 4) << 4)) ^ ((m & 7) << 4));
      af[kk] = *(const short8*)((const char*)A3 + ab);
    }
    #pragma unroll
    for(int i = 0; i < 2; ++i){
      int et = w + i * 8;
      f32x4 c = (f32x4){0,0,0,0};
      #pragma unroll
      for(int kk = 0; kk < 16; ++kk) c = MFMA(af[kk], w2p[((kk * 16 + et) << 6) + l], c);
      int e = et * 16 + (l & 15);
      float bb = b2v[e];
      #pragma unroll
      for(int j = 0; j < 4; ++j){
        int s = ((l >> 4) << 2) + j;
        if(s < 8) GR[s * 256 + e] = SL[s * 256 + e] + c[j] + bb;
      }
    }
  }
  __syncthreads();

  for(int i = t; i < 2048; i += 512){
    float v = GR[i];
    slots[(size_t)b * 2048 + i] = v;
    if(last) dout[(size_t)b * 2048 + i] = v;
  }
  {
    float4 g4 = ((const float4*)lnsg)[l], bb4 = ((const float4*)lnsb)[l];
    int s = w;
    float4 x4 = ((const float4*)(GR + s * 256))[l];
    float s1 = x4.x + x4.y + x4.z + x4.w;
    float s2 = x4.x*x4.x + x4.y*x4.y + x4.z*x4.z + x4.w*x4.w;
    #pragma unroll
    for(int o = 32; o >= 1; o >>= 1){ s1 += __shfl_xor(s1, o); s2 += __shfl_xor(s2, o); }
    float mean = s1 * (1.0f/256.0f);
    float inv  = rsqrtf(s2 * (1.0f/256.0f) - mean*mean + 1e-5f);
    float y0 = (x4.x-mean)*inv*g4.x + bb4.x;
    float y1 = (x4.y-mean)*inv*g4.y + bb4.y;
    float y2 = (x4.z-mean)*inv*g4.z + bb4.z;
    float y3 = (x4.w-mean)*inv*g4.w + bb4.w;
    int byte = s * 512 + ((l * 8) ^ ((s & 7) << 4));
    *(uint2*)((char*)A1 + byte) = make_uint2(pk2(y0,y1), pk2(y2,y3));
  }
  __syncthreads();
  {
    const int m = l & 15;
    short8 af[8];
    #pragma unroll
    for(int kk = 0; kk < 8; ++kk){
      int ab = m * 512 + (((kk * 64) + ((l >> 4) << 4)) ^ ((m & 7) << 4));
      af[kk] = *(const short8*)((const char*)A1 + ab);
    }
    #pragma unroll
    for(int i = 0; i < 2; ++i){
      int et = w + i * 8;
      f32x4 c = (f32x4){0,0,0,0};
      #pragma unroll
      for(int kk = 0; kk < 8; ++kk) c = MFMA(af[kk], wqp[((kk * 16 + et) << 6) + l], c);
      int e = et * 16 + (l & 15);
      #pragma unroll
      for(int j = 0; j < 4; ++j){
        int s = ((l >> 4) << 2) + j;
        if(s < 8) qbuf[(size_t)b * 2048 + s * 256 + e] = c[j] * 0.0625f;
      }
    }
  }
}

extern "C" void kernel_launch(void* const* d_in, const int* in_sizes, int n_in,
                              void* d_out, int out_size, void* d_ws, size_t ws_size,
                              hipStream_t stream)
{
  const float* inp   = (const float*)d_in[0];
  const float* noise = (const float*)d_in[1];
  const float* mu    = (const float*)d_in[2];
  const float* lsg   = (const float*)d_in[3];
  const float* lngi  = (const float*)d_in[4];
  const float* lnbi  = (const float*)d_in[5];
  const float* lngs  = (const float*)d_in[6];
  const float* lnbs  = (const float*)d_in[7];
  const float* lngm  = (const float*)d_in[8];
  const float* lnbm  = (const float*)d_in[9];
  const float* Wq    = (const float*)d_in[10];
  const float* Wk    = (const float*)d_in[11];
  const float* Wv    = (const float*)d_in[12];
  const float* Wih   = (const float*)d_in[13];
  const float* Whh   = (const float*)d_in[14];
  const float* bih   = (const float*)d_in[15];
  const float* bhh   = (const float*)d_in[16];
  const float* W1    = (const float*)d_in[17];
  const float* b1    = (const float*)d_in[18];
  const float* W2    = (const float*)d_in[19];
  const float* b2    = (const float*)d_in[20];
  float* dout = (float*)d_out;

  char* ws = (char*)d_ws;
  size_t off = 0;
  unsigned short* kb  = (unsigned short*)(ws + off); off += (size_t)BB*NN*DD*2;
  unsigned short* vT  = (unsigned short*)(ws + off); off += (size_t)BB*NN*DD*2;
  short8* wqp = (short8*)(ws + off); off += (size_t)256*256*2;
  short8* wkp = (short8*)(ws + off); off += (size_t)256*256*2;
  short8* wvp = (short8*)(ws + off); off += (size_t)256*256*2;
  short8* wihp= (short8*)(ws + off); off += (size_t)768*256*2;
  short8* whhp= (short8*)(ws + off); off += (size_t)768*256*2;
  short8* w1p = (short8*)(ws + off); off += (size_t)512*256*2;
  short8* w2p = (short8*)(ws + off); off += (size_t)256*512*2;
  float* qbuf = (float*)(ws + off); off += (size_t)512*256*4;
  float* slots= (float*)(ws + off); off += (size_t)512*256*4;
  float* pupd = (float*)(ws + off); off += (size_t)64*8*8*256*4;
  float* pms  = (float*)(ws + off); off += (size_t)64*8*8*2*4;

  PackDesc pd;
  const float* srcs[7] = {Wq, Wk, Wv, Wih, Whh, W1, W2};
  unsigned short* dsts[7] = {(unsigned short*)wqp, (unsigned short*)wkp, (unsigned short*)wvp,
                             (unsigned short*)wihp, (unsigned short*)whhp,
                             (unsigned short*)w1p, (unsigned short*)w2p};
  int ets[7] = {16, 16, 16, 48, 48, 32, 16};
  int ks [7] = {256, 256, 256, 256, 256, 256, 512};
  int cum = 0;
  for(int i = 0; i < 7; ++i){
    pd.src[i] = srcs[i]; pd.dst[i] = dsts[i]; pd.ET[i] = ets[i]; pd.K[i] = ks[i];
    pd.blkStart[i] = cum;
    cum += (ets[i] * 16 * ks[i] + 255) / 256;
  }
  pd.blkStart[7] = cum;
  pack_all_kernel<<<cum, 256, 0, stream>>>(pd);

  proj_kernel<<<4096, 256, 0, stream>>>(inp, lngi, lnbi, wkp, wvp, kb, vT);
  init_kernel<<<64, 256, 0, stream>>>(noise, mu, lsg, lngs, lnbs, wqp, slots, qbuf);

  for(int it = 0; it < 3; ++it){
    attn_kernel<<<512, 256, 0, stream>>>(kb, vT, qbuf, pupd, pms);
    update_kernel<<<64, 512, 0, stream>>>(pupd, pms, slots, qbuf, wihp, whhp,
        bih, bhh, w1p, b1, w2p, b2, lngs, lnbs, lngm, lnbm, wqp, dout, (it == 2) ? 1 : 0);
  }
}